// Round 1
// baseline (258.793 us; speedup 1.0000x reference)
//
#include <hip/hip_runtime.h>
#include <hip/hip_bf16.h>
#include <stdint.h>

#define Bn 64
#define Nn 25
#define Cn 128
#define Tn 256
#define EPSC 1e-5f

typedef short bf16x8 __attribute__((ext_vector_type(8)));
typedef float f32x4 __attribute__((ext_vector_type(4)));
typedef int   i32x4 __attribute__((ext_vector_type(4)));

// ws layout
static constexpr size_t X2T_BYTES  = (size_t)Bn * Nn * Tn * Cn * 2;  // 104,857,600
static constexpr size_t WEFF_OFF   = X2T_BYTES;
static constexpr size_t WEFF_BYTES = (size_t)3 * 128 * 128 * 2;      // 98,304
static constexpr size_t EPI_OFF    = WEFF_OFF + WEFF_BYTES;          // 16B aligned
static constexpr size_t ROWSUM_OFF = EPI_OFF + (size_t)7 * 128 * 4;
static constexpr size_t WS_NEEDED  = ROWSUM_OFF + 32 * 4;

__device__ __forceinline__ uint16_t f2bf(float f) {
    uint32_t u = __builtin_bit_cast(uint32_t, f);
    u = (u + 0x7FFFu + ((u >> 16) & 1u)) >> 16;  // RNE
    return (uint16_t)u;
}

// ---------------------------------------------------------------------------
// prep: Weff[k][o][c] = sum_i Wc[o,i,k] * Wg[i,c]  (bf16), plus epilogue tables
// grid 385 x 128
// ---------------------------------------------------------------------------
__global__ __launch_bounds__(128) void prep_kernel(
    const float* __restrict__ adj, const float* __restrict__ Wg,
    const float* __restrict__ bg,  const float* __restrict__ Wc,
    const float* __restrict__ bc,
    const float* __restrict__ tg,  const float* __restrict__ tb_,
    const float* __restrict__ tm,  const float* __restrict__ tv,
    const float* __restrict__ bng, const float* __restrict__ bnb,
    const float* __restrict__ bnm, const float* __restrict__ bnv,
    uint16_t* __restrict__ weff, float* __restrict__ epi, float* __restrict__ rowsum)
{
    int blk = blockIdx.x;
    int tid = threadIdx.x;
    if (blk < 384) {
        int k = blk >> 7, o = blk & 127;
        float acc = 0.f;
        for (int i = 0; i < 128; ++i) {
            float wc = Wc[(o * 128 + i) * 3 + k];
            acc = fmaf(wc, Wg[i * 128 + tid], acc);
        }
        weff[((size_t)(k * 128 + o)) * 128 + tid] = f2bf(acc);
    } else {
        int o = tid;
        float b0 = 0.f, b1 = 0.f, b2 = 0.f;
        for (int i = 0; i < 128; ++i) {
            float g = bg[i];
            b0 = fmaf(Wc[(o * 128 + i) * 3 + 0], g, b0);
            b1 = fmaf(Wc[(o * 128 + i) * 3 + 1], g, b1);
            b2 = fmaf(Wc[(o * 128 + i) * 3 + 2], g, b2);
        }
        float a1  = tg[o] * rsqrtf(tv[o] + EPSC);
        float c1p = tb_[o] - a1 * tm[o] + a1 * bc[o];   // folds b_conv
        float a2  = bng[o] * rsqrtf(bnv[o] + EPSC);
        float c2  = bnb[o] - a2 * bnm[o];
        epi[0 * 128 + o] = a1;
        epi[1 * 128 + o] = c1p;
        epi[2 * 128 + o] = a2;
        epi[3 * 128 + o] = c2;
        epi[4 * 128 + o] = a1 * b0;   // g0 (k=0 bias term, valid when t>0)
        epi[5 * 128 + o] = a1 * b1;   // g1 (always valid)
        epi[6 * 128 + o] = a1 * b2;   // g2 (valid when t<255)
        if (tid < Nn) {
            float s = 0.f;
            for (int n = 0; n < Nn; ++n) s += adj[tid * Nn + n];
            rowsum[tid] = s;
        }
    }
}

// ---------------------------------------------------------------------------
// adjmix: x2T[b][m][t][c] (bf16) = sum_n adj[m,n] * x[b][n][c][t]
// tile 32c x 32t per block, 25 accumulators/thread, LDS-bounce transpose
// grid 2048 x 256
// ---------------------------------------------------------------------------
__global__ __launch_bounds__(256) void adjmix_kernel(
    const float* __restrict__ x, const float* __restrict__ adj,
    uint16_t* __restrict__ x2t)
{
    __shared__ float adjs[Nn * Nn];
    __shared__ float tr[32][33];

    int bid = blockIdx.x;
    int b  = bid >> 5;
    int rem = bid & 31;
    int cb = rem >> 3, tb = rem & 7;
    int c0 = cb * 32, t0 = tb * 32;
    int tid = threadIdx.x;

    for (int i = tid; i < Nn * Nn; i += 256) adjs[i] = adj[i];
    __syncthreads();

    int cl = tid >> 3;          // 0..31 (channel)
    int t4 = (tid & 7) * 4;     // 0..28 (t, 4 per thread)

    float acc[Nn][4];
#pragma unroll
    for (int m = 0; m < Nn; ++m)
#pragma unroll
        for (int j = 0; j < 4; ++j) acc[m][j] = 0.f;

    for (int n = 0; n < Nn; ++n) {
        const float4 v = *reinterpret_cast<const float4*>(
            x + (((size_t)(b * Nn + n) * Cn + c0 + cl) * Tn + t0 + t4));
#pragma unroll
        for (int m = 0; m < Nn; ++m) {
            float a = adjs[m * Nn + n];
            acc[m][0] = fmaf(a, v.x, acc[m][0]);
            acc[m][1] = fmaf(a, v.y, acc[m][1]);
            acc[m][2] = fmaf(a, v.z, acc[m][2]);
            acc[m][3] = fmaf(a, v.w, acc[m][3]);
        }
    }

    int c2   = tid & 15;   // c pair index (0..15)
    int trow0 = tid >> 4;  // 0..15

#pragma unroll
    for (int m = 0; m < Nn; ++m) {
        __syncthreads();
        tr[cl][t4 + 0] = acc[m][0];
        tr[cl][t4 + 1] = acc[m][1];
        tr[cl][t4 + 2] = acc[m][2];
        tr[cl][t4 + 3] = acc[m][3];
        __syncthreads();
#pragma unroll
        for (int p = 0; p < 2; ++p) {
            int trow = trow0 + p * 16;
            uint32_t h0 = f2bf(tr[c2 * 2 + 0][trow]);
            uint32_t h1 = f2bf(tr[c2 * 2 + 1][trow]);
            uint32_t u = h0 | (h1 << 16);
            size_t elem = ((size_t)(b * Nn + m) * Tn + (t0 + trow)) * Cn + c0 + c2 * 2;
            *reinterpret_cast<uint32_t*>(x2t + elem) = u;
        }
    }
}

// ---------------------------------------------------------------------------
// conv: per (b, m, t-block of 64): y[o][t] = sum_{k,c} Weff[k][o][c]*x2[c][t+k-1]
// then fused bias/BN/ReLU/residual/BN/ReLU epilogue. MFMA 16x16x32 bf16.
// block 256 threads (4 waves), wave tile 32o x 64t. grid 6400 x 256
// ---------------------------------------------------------------------------
__global__ __launch_bounds__(256) void conv_kernel(
    const uint16_t* __restrict__ x2t, const uint16_t* __restrict__ weff,
    const float* __restrict__ x, const float* __restrict__ epi,
    const float* __restrict__ rowsum, float* __restrict__ out)
{
    __shared__ uint16_t lds[66 * 128];  // 16896 B, XOR-swizzled rows

    int bid = blockIdx.x;
    int b   = bid / 100;
    int rem = bid % 100;
    int m   = rem >> 2;
    int tb  = rem & 3;
    int t0  = tb * 64;

    int tid = threadIdx.x;
    int w = tid >> 6;   // wave 0..3 -> o range [32w, 32w+32)
    int l = tid & 63;
    int g = l >> 4;     // 0..3
    int r = l & 15;

    // ---- stage x2T rows (t0-1 .. t0+64) into LDS rows 0..65, swizzled ----
    const size_t x2base = (size_t)(b * Nn + m) * Tn * Cn;  // elements
    {
        int row_t = tid >> 4;  // 0..15
        int cg    = tid & 15;  // 16B column group
#pragma unroll
        for (int pass = 0; pass < 5; ++pass) {
            int lrow = pass * 16 + row_t;
            if (lrow < 66) {
                int gt = t0 - 1 + lrow;
                i32x4 v = {0, 0, 0, 0};
                if (gt >= 0 && gt < Tn)
                    v = *reinterpret_cast<const i32x4*>(
                        (const char*)x2t + (x2base + (size_t)gt * Cn) * 2 + cg * 16);
                int lbyte = (lrow * 256 + cg * 16) ^ ((lrow & 7) << 4);
                *reinterpret_cast<i32x4*>((char*)lds + lbyte) = v;
            }
        }
    }
    __syncthreads();

    f32x4 acc[2][4];
#pragma unroll
    for (int f = 0; f < 2; ++f)
#pragma unroll
        for (int j = 0; j < 4; ++j) acc[f][j] = (f32x4){0.f, 0.f, 0.f, 0.f};

    const short* wptr = (const short*)weff;
#pragma unroll
    for (int kk = 0; kk < 3; ++kk) {
#pragma unroll
        for (int cc = 0; cc < 4; ++cc) {
            bf16x8 a[2];
#pragma unroll
            for (int f = 0; f < 2; ++f) {
                int o = w * 32 + f * 16 + r;
                a[f] = *reinterpret_cast<const bf16x8*>(
                    wptr + ((size_t)(kk * 128 + o) * 128 + cc * 32 + g * 8));
            }
            bf16x8 bf[4];
#pragma unroll
            for (int j = 0; j < 4; ++j) {
                int lrow  = j * 16 + r + kk;
                int lbyte = (lrow * 256 + (cc * 32 + g * 8) * 2) ^ ((lrow & 7) << 4);
                bf[j] = *reinterpret_cast<const bf16x8*>((const char*)lds + lbyte);
            }
#pragma unroll
            for (int f = 0; f < 2; ++f)
#pragma unroll
                for (int j = 0; j < 4; ++j)
                    acc[f][j] = __builtin_amdgcn_mfma_f32_16x16x32_bf16(
                        a[f], bf[j], acc[f][j], 0, 0, 0);
        }
    }

    // ---- epilogue ----
    float rs = rowsum[m];
    const size_t obase_addr = (size_t)(b * Nn + m) * Cn;
#pragma unroll
    for (int f = 0; f < 2; ++f) {
        int ob = w * 32 + f * 16 + g * 4;
        f32x4 a1  = *reinterpret_cast<const f32x4*>(epi + 0 * 128 + ob);
        f32x4 c1p = *reinterpret_cast<const f32x4*>(epi + 1 * 128 + ob);
        f32x4 a2  = *reinterpret_cast<const f32x4*>(epi + 2 * 128 + ob);
        f32x4 c2  = *reinterpret_cast<const f32x4*>(epi + 3 * 128 + ob);
        f32x4 g0  = *reinterpret_cast<const f32x4*>(epi + 4 * 128 + ob);
        f32x4 g1  = *reinterpret_cast<const f32x4*>(epi + 5 * 128 + ob);
        f32x4 g2  = *reinterpret_cast<const f32x4*>(epi + 6 * 128 + ob);
#pragma unroll
        for (int j = 0; j < 4; ++j) {
            int t = t0 + j * 16 + r;
            f32x4 gb = g1;
            if (t > 0)       gb = gb + g0;
            if (t < Tn - 1)  gb = gb + g2;
#pragma unroll
            for (int q = 0; q < 4; ++q) {
                int o = ob + q;
                float y1 = acc[f][j][q];
                float z  = a1[q] * y1 + rs * gb[q] + c1p[q];
                z = fmaxf(z, 0.f);
                size_t idx = (obase_addr + o) * Tn + t;
                float wv = z + x[idx];
                float ov = fmaxf(a2[q] * wv + c2[q], 0.f);
                out[idx] = ov;
            }
        }
    }
}

// ---------------------------------------------------------------------------
extern "C" void kernel_launch(void* const* d_in, const int* in_sizes, int n_in,
                              void* d_out, int out_size, void* d_ws, size_t ws_size,
                              hipStream_t stream) {
    const float* x    = (const float*)d_in[0];
    const float* adj  = (const float*)d_in[1];
    const float* Wg   = (const float*)d_in[2];
    const float* bg   = (const float*)d_in[3];
    const float* Wc   = (const float*)d_in[4];
    const float* bc   = (const float*)d_in[5];
    const float* tg   = (const float*)d_in[6];
    const float* tb_  = (const float*)d_in[7];
    const float* tm   = (const float*)d_in[8];
    const float* tv   = (const float*)d_in[9];
    const float* bng  = (const float*)d_in[10];
    const float* bnb  = (const float*)d_in[11];
    const float* bnm  = (const float*)d_in[12];
    const float* bnv  = (const float*)d_in[13];

    if (ws_size < WS_NEEDED) return;  // scratch too small: bail (will fail loudly)

    char* ws = (char*)d_ws;
    uint16_t* x2t    = (uint16_t*)ws;
    uint16_t* weff   = (uint16_t*)(ws + WEFF_OFF);
    float*    epi    = (float*)(ws + EPI_OFF);
    float*    rowsum = (float*)(ws + ROWSUM_OFF);
    float*    out    = (float*)d_out;

    prep_kernel<<<385, 128, 0, stream>>>(adj, Wg, bg, Wc, bc, tg, tb_, tm, tv,
                                         bng, bnb, bnm, bnv, weff, epi, rowsum);
    adjmix_kernel<<<2048, 256, 0, stream>>>(x, adj, x2t);
    conv_kernel<<<6400, 256, 0, stream>>>(x2t, weff, x, epi, rowsum, out);
}